// Round 1
// baseline (53.366 us; speedup 1.0000x reference)
//
#include <hip/hip_runtime.h>
#include <stdint.h>
#include <math.h>

// Problem geometry (fixed by reference)
#define HWPIX 65536         // 256*256
#define NCH   18
#define NHYP  1024
#define NK    9
#define NBK   72            // B*K = 8*9
#define NPIXBLK 512         // blocks per side in pixel kernel (512*256*4 = 524288 pixels)
#define INV_LOG2 1.4426950408889634f
#define TINYF 1.1754943508222875e-38f

// ws layout (floats)
#define OFS_VOTE 64
#define OFS_CNT  (OFS_VOTE + 2 * NPIXBLK)
#define OFS_SEG  (OFS_CNT  + 2 * NPIXBLK)
#define OFS_KP   (OFS_SEG  + 2 * NPIXBLK)
#define OFS_ENT  (OFS_KP   + 2 * NBK)
#define OFS_Y    (OFS_ENT  + 2 * NBK)

// ---- Threefry-2x32, 20 rounds (JAX-compatible) ----
__host__ __device__ inline void tf2x32(uint32_t k0, uint32_t k1,
                                       uint32_t x0, uint32_t x1,
                                       uint32_t& o0, uint32_t& o1) {
  uint32_t ks2 = k0 ^ k1 ^ 0x1BD11BDAu;
  x0 += k0; x1 += k1;
#define TFR(r) { x0 += x1; x1 = (x1 << (r)) | (x1 >> (32 - (r))); x1 ^= x0; }
  TFR(13) TFR(15) TFR(26) TFR(6)   x0 += k1;  x1 += ks2 + 1u;
  TFR(17) TFR(29) TFR(16) TFR(24)  x0 += ks2; x1 += k0 + 2u;
  TFR(13) TFR(15) TFR(26) TFR(6)   x0 += k0;  x1 += k1 + 3u;
  TFR(17) TFR(29) TFR(16) TFR(24)  x0 += k1;  x1 += ks2 + 4u;
  TFR(13) TFR(15) TFR(26) TFR(6)   x0 += ks2; x1 += k0 + 5u;
#undef TFR
  o0 = x0; o1 = x1;
}

__device__ inline float blk_sum(float v, float* sm) {
  int t = threadIdx.x;
  sm[t] = v; __syncthreads();
  for (int off = 128; off > 0; off >>= 1) {
    if (t < off) sm[t] += sm[t + off];
    __syncthreads();
  }
  float r = sm[0]; __syncthreads();
  return r;
}

__device__ inline float nll2(float s0, float s1, int lbl) {
  float mx = fmaxf(s0, s1);
  float l = mx + logf(expf(s0 - mx) + expf(s1 - mx));
  return l - (lbl ? s1 : s0);
}

// ---- Kernel 1: masked smooth-L1 vote sum + mask count + seg CE over pixels ----
__global__ __launch_bounds__(256) void pixel_kernel(
    const float* __restrict__ vpL, const float* __restrict__ vgL,
    const int*   __restrict__ mkL, const float* __restrict__ sgL,
    const float* __restrict__ vpR, const float* __restrict__ vgR,
    const int*   __restrict__ mkR, const float* __restrict__ sgR,
    float* __restrict__ ws) {
  const int side = blockIdx.y;
  const float* vp = side ? vpR : vpL;
  const float* vg = side ? vgR : vgL;
  const int*   mk = side ? mkR : mkL;
  const float* sg = side ? sgR : sgL;

  const int g  = blockIdx.x * 256 + threadIdx.x;   // 0..131071
  const int p0 = g * 4;                            // flat pixel index over B*H*W
  const int b  = p0 >> 16;                         // /65536
  const int hw = p0 & (HWPIX - 1);

  const int4 m4 = *(const int4*)(mk + p0);
  const float w0 = (float)m4.x, w1 = (float)m4.y, w2 = (float)m4.z, w3 = (float)m4.w;

  float vote = 0.f;
  const size_t vbase = (size_t)b * (NCH * HWPIX) + hw;
#pragma unroll
  for (int c = 0; c < NCH; ++c) {
    const float4 p = *(const float4*)(vp + vbase + (size_t)c * HWPIX);
    const float4 q = *(const float4*)(vg + vbase + (size_t)c * HWPIX);
    float dd;
    dd = fabsf(p.x - q.x) * w0; vote += (dd < 1.f) ? 0.5f * dd * dd : dd - 0.5f;
    dd = fabsf(p.y - q.y) * w1; vote += (dd < 1.f) ? 0.5f * dd * dd : dd - 0.5f;
    dd = fabsf(p.z - q.z) * w2; vote += (dd < 1.f) ? 0.5f * dd * dd : dd - 0.5f;
    dd = fabsf(p.w - q.w) * w3; vote += (dd < 1.f) ? 0.5f * dd * dd : dd - 0.5f;
  }
  const float cnt = w0 + w1 + w2 + w3;

  const size_t sbase = (size_t)b * (2 * HWPIX) + hw;
  const float4 s0 = *(const float4*)(sg + sbase);
  const float4 s1 = *(const float4*)(sg + sbase + HWPIX);
  float seg = 0.f;
  seg += nll2(s0.x, s1.x, m4.x);
  seg += nll2(s0.y, s1.y, m4.y);
  seg += nll2(s0.z, s1.z, m4.z);
  seg += nll2(s0.w, s1.w, m4.w);

  __shared__ float sm[256];
  float v  = blk_sum(vote, sm);
  float c2 = blk_sum(cnt, sm);
  float sg2 = blk_sum(seg, sm);
  if (threadIdx.x == 0) {
    ws[OFS_VOTE + side * NPIXBLK + blockIdx.x] = v;
    ws[OFS_CNT  + side * NPIXBLK + blockIdx.x] = c2;
    ws[OFS_SEG  + side * NPIXBLK + blockIdx.x] = sg2;
  }
}

// ---- Kernel 2: per-(b,k,side) softmax (kp loss + entropy) and gumbel-argmax
//      categorical sample -> selected y coordinate ----
__global__ __launch_bounds__(256) void hyp_kernel(
    const float* __restrict__ scL, const float* __restrict__ kpL,
    const float* __restrict__ k2L, const float* __restrict__ ofL,
    const float* __restrict__ scR, const float* __restrict__ kpR,
    const float* __restrict__ k2R, const float* __restrict__ ofR,
    const float* __restrict__ aPtr,
    uint32_t kLa, uint32_t kLb, uint32_t kRa, uint32_t kRb,
    float* __restrict__ ws) {
  const int side = blockIdx.y;
  const float* sc = side ? scR : scL;
  const float* kp = side ? kpR : kpL;
  const float* k2 = side ? k2R : k2L;
  const float* of = side ? ofR : ofL;
  const uint32_t K0 = side ? kRa : kLa;
  const uint32_t K1 = side ? kRb : kLb;
  const int bk = blockIdx.x;          // 0..71
  const int b = bk / NK, k = bk % NK;
  const int t = threadIdx.x;
  const float a = aPtr[0];
  const float kx = k2[(b * NK + k) * 2 + 0];
  const float ky = k2[(b * NK + k) * 2 + 1];
  const float2* kp2 = (const float2*)kp;

  float s[4], d[4], gv[4];
#pragma unroll
  for (int j = 0; j < 4; ++j) {
    const int n = t + j * 256;
    const size_t idx = ((size_t)b * NHYP + n) * NK + k;   // row-major flat index of (b,n,k)
    s[j] = a * sc[idx];
    const float2 xy = kp2[idx];
    const float dx = xy.x - kx, dy = xy.y - ky;
    d[j] = sqrtf(dx * dx + dy * dy);
    // JAX partitionable random bits: bits = out0 ^ out1 of threefry(key, (0, flat_idx))
    uint32_t o0, o1;
    tf2x32(K0, K1, 0u, (uint32_t)idx, o0, o1);
    const uint32_t bits = o0 ^ o1;
    float u = __uint_as_float((bits >> 9) | 0x3F800000u) - 1.0f;   // [0,1)
    u = fmaxf(TINYF, u * (1.0f - TINYF) + TINYF);                  // uniform(tiny, 1)
    gv[j] = -logf(-logf(u)) + s[j];                                // gumbel + logits
  }

  __shared__ float sm[256];
  __shared__ int   si[256];

  // block max of logits
  float mx = fmaxf(fmaxf(s[0], s[1]), fmaxf(s[2], s[3]));
  sm[t] = mx; __syncthreads();
  for (int off = 128; off > 0; off >>= 1) {
    if (t < off) sm[t] = fmaxf(sm[t], sm[t + off]);
    __syncthreads();
  }
  mx = sm[0]; __syncthreads();

  float Z = 0.f, Sd = 0.f, Ss = 0.f;
#pragma unroll
  for (int j = 0; j < 4; ++j) {
    const float e = expf(s[j] - mx);
    Z  += e;
    Sd += e * d[j];
    Ss += e * (s[j] - mx);
  }
  Z  = blk_sum(Z, sm);
  Sd = blk_sum(Sd, sm);
  Ss = blk_sum(Ss, sm);

  // argmax of gumbel+logits, first-index tie-break (matches jnp.argmax)
  float bv = gv[0]; int bi = t;
#pragma unroll
  for (int j = 1; j < 4; ++j) {
    const int n = t + j * 256;
    if (gv[j] > bv) { bv = gv[j]; bi = n; }
  }
  sm[t] = bv; si[t] = bi; __syncthreads();
  for (int off = 128; off > 0; off >>= 1) {
    if (t < off) {
      const float v2 = sm[t + off]; const int i2 = si[t + off];
      if (v2 > sm[t] || (v2 == sm[t] && i2 < si[t])) { sm[t] = v2; si[t] = i2; }
    }
    __syncthreads();
  }

  if (t == 0) {
    ws[OFS_KP  + side * NBK + bk] = Sd / Z;
    ws[OFS_ENT + side * NBK + bk] = (logf(Z) - Ss / Z) * INV_LOG2;  // entropy in bits
    const int n = si[0];
    ws[OFS_Y + side * NBK + bk] =
        kp2[((size_t)b * NHYP + n) * NK + k].y + of[b * 2 + 1];
  }
}

// ---- Kernel 3: stage-2 reductions + scalar combine ----
__global__ __launch_bounds__(256) void final_kernel(
    const int* __restrict__ epochPtr, const float* __restrict__ ws,
    float* __restrict__ out) {
  __shared__ float sm[256];
  const int t = threadIdx.x;
  float voteS[2], cntS[2], segS[2], kpS[2], entS[2];
  for (int side = 0; side < 2; ++side) {
    float a;
    a = 0.f; for (int j = t; j < NPIXBLK; j += 256) a += ws[OFS_VOTE + side * NPIXBLK + j];
    voteS[side] = blk_sum(a, sm);
    a = 0.f; for (int j = t; j < NPIXBLK; j += 256) a += ws[OFS_CNT + side * NPIXBLK + j];
    cntS[side] = blk_sum(a, sm);
    a = 0.f; for (int j = t; j < NPIXBLK; j += 256) a += ws[OFS_SEG + side * NPIXBLK + j];
    segS[side] = blk_sum(a, sm);
    a = (t < NBK) ? ws[OFS_KP + side * NBK + t] : 0.f;
    kpS[side] = blk_sum(a, sm);
    a = 0.f;
    if (t < 8) {
      float es = 0.f;
      for (int k = 0; k < NK; ++k) es += ws[OFS_ENT + side * NBK + t * NK + k];
      a = fabsf(es / (float)NK - 6.0f);
    }
    entS[side] = blk_sum(a, sm);
  }
  float e = 0.f;
  if (t < NBK) {
    const float dy = fabsf(ws[OFS_Y + t] - ws[OFS_Y + NBK + t]);
    e = isfinite(dy) ? dy : 0.f;
  }
  const float epiSum = blk_sum(e, sm);

  if (t == 0) {
    const float voteL = (cntS[0] > 0.f) ? voteS[0] / fmaxf(cntS[0], 1.f) / (float)NCH : voteS[0];
    const float voteR = (cntS[1] > 0.f) ? voteS[1] / fmaxf(cntS[1], 1.f) / (float)NCH : voteS[1];
    const float segL = segS[0] / 524288.f;
    const float segR = segS[1] / 524288.f;
    const float kpLm = kpS[0] / (float)NBK, kpRm = kpS[1] / (float)NBK;
    const float entL = entS[0] / 8.f, entR = entS[1] / 8.f;

    const float vote_loss = 0.5f * (voteL + voteR);
    const float seg_loss  = 0.5f * (segL + segR);
    const float kp_loss   = 0.5f * (kpLm + kpRm);
    const float ent_loss  = 0.5f * (entL + entR);
    const float kp_w  = 1.f / (1.f + expf(-0.5f * (20.f - kp_loss)));
    const float vote_w = 1.f - kp_w;
    float vertex;
    if (epochPtr[0] > 49) {
      const float epi = epiSum / (float)NBK;
      vertex = kp_w * (kp_loss + epi) + vote_w * vote_loss;
    } else {
      vertex = kp_w * kp_loss + vote_w * vote_loss;
    }
    out[0] = vertex + ent_loss + seg_loss;
  }
}

extern "C" void kernel_launch(void* const* d_in, const int* in_sizes, int n_in,
                              void* d_out, int out_size, void* d_ws, size_t ws_size,
                              hipStream_t stream) {
  (void)in_sizes; (void)n_in; (void)out_size; (void)ws_size;
  const float* vpL = (const float*)d_in[0];
  const float* vgL = (const float*)d_in[1];
  const int*   mkL = (const int*)  d_in[2];
  const float* sgL = (const float*)d_in[3];
  const float* kpL = (const float*)d_in[4];
  const float* scL = (const float*)d_in[5];
  const float* k2L = (const float*)d_in[6];
  const float* ofL = (const float*)d_in[7];
  const float* vpR = (const float*)d_in[8];
  const float* vgR = (const float*)d_in[9];
  const int*   mkR = (const int*)  d_in[10];
  const float* sgR = (const float*)d_in[11];
  const float* kpR = (const float*)d_in[12];
  const float* scR = (const float*)d_in[13];
  const float* k2R = (const float*)d_in[14];
  const float* ofR = (const float*)d_in[15];
  const float* aP  = (const float*)d_in[16];
  const int*   epP = (const int*)  d_in[17];
  float* ws  = (float*)d_ws;
  float* out = (float*)d_out;

  // jax.random.split(jax.random.key(1234)) — partitionable ("foldlike") split:
  // kL = threefry(key, (0,0)), kR = threefry(key, (0,1)), key = [0, 1234]
  uint32_t kLa, kLb, kRa, kRb;
  tf2x32(0u, 1234u, 0u, 0u, kLa, kLb);
  tf2x32(0u, 1234u, 0u, 1u, kRa, kRb);

  pixel_kernel<<<dim3(NPIXBLK, 2), 256, 0, stream>>>(
      vpL, vgL, mkL, sgL, vpR, vgR, mkR, sgR, ws);
  hyp_kernel<<<dim3(NBK, 2), 256, 0, stream>>>(
      scL, kpL, k2L, ofL, scR, kpR, k2R, ofR, aP, kLa, kLb, kRa, kRb, ws);
  final_kernel<<<1, 256, 0, stream>>>(epP, ws, out);
}